// Round 10
// baseline (170.963 us; speedup 1.0000x reference)
//
#include <hip/hip_runtime.h>
#include <cstdint>
#include <cstddef>

#define BB  2
#define TT  2048
#define CC  1024
#define NHH 16
#define HSS 64
#define BT  (BB*TT)   // 4096

#define LOG2E 1.44269504088896f
#define S0INIT (-28.8539008f)   // -20 * log2(e)

typedef unsigned short u16;
typedef unsigned int u32;
typedef __attribute__((ext_vector_type(2))) unsigned int u32x2;
typedef _Float16 f16;
typedef __attribute__((ext_vector_type(8))) _Float16 f16x8;
typedef __attribute__((ext_vector_type(8))) __bf16 bf16x8;
typedef __attribute__((ext_vector_type(4))) float f32x4;

__device__ __forceinline__ u16 f2bf(float f) {
    union { float f; u32 u; } x; x.f = f;
    return (u16)((x.u + 0x7fffu + ((x.u >> 16) & 1u)) >> 16);
}
__device__ __forceinline__ u16 f2h(float f) {
    union { f16 h; u16 u; } x; x.h = (f16)f;
    return x.u;
}
// packed f32 pair -> bf16x2 in one u32 (RNE), single VALU op
__device__ __forceinline__ u32 cvtpk_bf16(float lo, float hi) {
    u32 r;
    asm("v_cvt_pk_bf16_f32 %0, %1, %2" : "=v"(r) : "v"(lo), "v"(hi));
    return r;
}

#define MFMA_BF(a,b,c) __builtin_amdgcn_mfma_f32_16x16x32_bf16((a),(b),(c),0,0,0)
#define MFMA_F16(a,b,c) __builtin_amdgcn_mfma_f32_16x16x32_f16((a),(b),(c),0,0,0)

// async global->LDS, 16B/lane; LDS dest = wave-uniform base + lane*16
__device__ __forceinline__ void gld16(const u16* g, u16* l) {
    __builtin_amdgcn_global_load_lds(
        (const __attribute__((address_space(1))) unsigned int*)g,
        (__attribute__((address_space(3))) unsigned int*)l, 16, 0, 0);
}

// ---------------------------------------------------------------------------
// convert_xw: merged converter.
// bid < 2048: x fp32 -> Xf fp16. bid >= 2048: W -> WT fp16 via LDS transpose.
// ---------------------------------------------------------------------------
__global__ __launch_bounds__(256) void convert_xw(
    const float* __restrict__ X, const float* __restrict__ Wk,
    const float* __restrict__ Wv, u16* __restrict__ Xf,
    u16* __restrict__ WkT, u16* __restrict__ WvT)
{
    __shared__ __align__(16) u16 LH[64][72];
    const int bid = blockIdx.x;
    const int tid = threadIdx.x;
    if (bid < 2048) {
        const int idx = (bid * 256 + tid) * 8;
        const float4 a = *(const float4*)&X[idx];
        const float4 b = *(const float4*)&X[idx + 4];
        float v[8] = {a.x, a.y, a.z, a.w, b.x, b.y, b.z, b.w};
        union { uint4 u; u16 s[8]; } H;
        #pragma unroll
        for (int u = 0; u < 8; ++u) H.s[u] = f2h(v[u]);
        *(uint4*)&Xf[idx] = H.u;
        return;
    }
    const int bid2 = bid - 2048;          // [0,512)
    const bool isK = (bid2 >> 8) == 0;
    const int rem = bid2 & 255;
    const int n0 = (rem & 15) * 64, k0 = (rem >> 4) * 64;
    const float* W = isK ? Wk : Wv;
    u16* WT = isK ? WkT : WvT;
    {
        const int row = tid >> 2, coff = (tid & 3) * 16;
        const float* g = &W[(size_t)(k0 + row) * CC + n0 + coff];
        #pragma unroll
        for (int u = 0; u < 16; ++u) LH[row][coff + u] = f2h(g[u]);
    }
    __syncthreads();
    {
        const int n = tid >> 2, kc = (tid & 3) * 16;
        union { uint4 u[2]; u16 s[16]; } Hq;
        #pragma unroll
        for (int u = 0; u < 16; ++u) Hq.s[u] = LH[kc + u][n];
        uint4* ph = (uint4*)&WT[(size_t)(n0 + n) * CC + k0 + kc];
        ph[0] = Hq.u[0]; ph[1] = Hq.u[1];
    }
}

// ---------------------------------------------------------------------------
// proj_kernel: R7 version unchanged (passing). 128x128 fp16 GEMM, BK=32,
// 4-buffer gld16 staging 2 ahead, counted vmcnt + builtin s_barrier,
// z->XCD-half mapping. z=0: Kf fp16 (log2e-prescaled); z=1: Vt bf16 [b][h][d][T].
// ---------------------------------------------------------------------------
__global__ __launch_bounds__(256) void proj_kernel(
    const u16* __restrict__ Xf, const u16* __restrict__ WkT,
    const u16* __restrict__ WvT,
    const float* __restrict__ bk, const float* __restrict__ bv,
    u16* __restrict__ Kf, u16* __restrict__ Vt)
{
    __shared__ __align__(16) u16 SM[4][8192];  // 4 bufs x (A 8KB + B 8KB) = 64KB

    const int id = blockIdx.x;
    const int xcd = id & 7;
    const int z = xcd >> 2, xcd4 = xcd & 3;
    const int idx = id >> 3;
    const int n0 = (idx & 7) * 128;
    const int m0 = (xcd4 * 8 + (idx >> 3)) * 128;
    const bool isK = (z == 0);
    const u16* WT = isK ? WkT : WvT;

    const int tid = threadIdx.x;
    const int w = tid >> 6, lane = tid & 63;
    const int quad = lane >> 4, l15 = lane & 15;
    const int wm = (w >> 1) * 64, wn = (w & 1) * 64;

    const u16* src = (w < 2) ? Xf : WT;
    const int rbase = (w < 2) ? m0 : n0;
    int srow[4], scg[4];
    #pragma unroll
    for (int t = 0; t < 4; ++t) {
        const int ci = (w & 1) * 256 + t * 64 + lane;
        const int r = ci >> 2;
        srow[t] = r;
        scg[t] = ((ci & 3) - r - (r >> 2)) & 3;
    }
    const int dhalf = ((w >= 2) ? 4096 : 0) + (w & 1) * 2048;
    const u16* gsrc[4];
    #pragma unroll
    for (int t = 0; t < 4; ++t)
        gsrc[t] = src + (size_t)(rbase + srow[t]) * CC + scg[t] * 8;

    const char* smb = (const char*)&SM[0][0];
    int aoff[4], boff[4];
    #pragma unroll
    for (int i = 0; i < 4; ++i) {
        const int r = wm + i * 16 + l15;
        aoff[i] = r * 64 + ((quad + r + (r >> 2)) & 3) * 16;
    }
    #pragma unroll
    for (int j = 0; j < 4; ++j) {
        const int r = wn + j * 16 + l15;
        boff[j] = 8192 + r * 64 + ((quad + r + (r >> 2)) & 3) * 16;
    }

    f32x4 acc[4][4] = {};

#define PSTAGE(K, BI)                                                   \
    { u16* dst = &SM[BI][dhalf];                                        \
      _Pragma("unroll")                                                 \
      for (int t = 0; t < 4; ++t)                                       \
          gld16(gsrc[t] + (K) * 32, dst + t * 512); }

    PSTAGE(0, 0);
    PSTAGE(1, 1);

    for (int ki = 0; ki < 32; ++ki) {
        const int buf = ki & 3;
        if (ki < 30) PSTAGE(ki + 2, (ki + 2) & 3);
        if (ki < 30)       asm volatile("s_waitcnt vmcnt(8)" ::: "memory");
        else if (ki == 30) asm volatile("s_waitcnt vmcnt(4)" ::: "memory");
        else               asm volatile("s_waitcnt vmcnt(0)" ::: "memory");
        __builtin_amdgcn_sched_barrier(0);
        __builtin_amdgcn_s_barrier();
        __builtin_amdgcn_sched_barrier(0);
        const char* pb = smb + buf * 16384;
        f16x8 ah[4];
        #pragma unroll
        for (int i = 0; i < 4; ++i) ah[i] = *(const f16x8*)(pb + aoff[i]);
        #pragma unroll
        for (int j = 0; j < 4; ++j) {
            f16x8 bh = *(const f16x8*)(pb + boff[j]);
            #pragma unroll
            for (int i = 0; i < 4; ++i)
                acc[i][j] = MFMA_F16(ah[i], bh, acc[i][j]);
        }
    }
#undef PSTAGE

    __syncthreads();
    u16* XL = &SM[0][0];

    if (isK) {
        #pragma unroll
        for (int j = 0; j < 4; ++j) {
            const float bias = bk[n0 + wn + j * 16 + l15];
            #pragma unroll
            for (int i = 0; i < 4; ++i)
                #pragma unroll
                for (int r = 0; r < 4; ++r)
                    XL[(wm + i * 16 + quad * 4 + r) * 136 + wn + j * 16 + l15] =
                        f2h((acc[i][j][r] + bias) * LOG2E);
        }
        __syncthreads();
        const int r = tid >> 1, half = tid & 1;
        #pragma unroll
        for (int t = 0; t < 8; ++t)
            *(uint4*)&Kf[(size_t)(m0 + r) * CC + n0 + half * 64 + t * 8] =
                *(const uint4*)&XL[r * 136 + half * 64 + t * 8];
    } else {
        #pragma unroll
        for (int j = 0; j < 4; ++j) {
            const float bias = bv[n0 + wn + j * 16 + l15];
            #pragma unroll
            for (int i = 0; i < 4; ++i) {
                uint2 pk;
                pk.x = (u32)f2bf(acc[i][j][0] + bias) |
                       ((u32)f2bf(acc[i][j][1] + bias) << 16);
                pk.y = (u32)f2bf(acc[i][j][2] + bias) |
                       ((u32)f2bf(acc[i][j][3] + bias) << 16);
                *(uint2*)&XL[(wn + j * 16 + l15) * 136 + wm + i * 16 + quad * 4] = pk;
            }
        }
        __syncthreads();
        const int nl = tid >> 1, half = tid & 1;
        const int d = (n0 + nl) & (HSS - 1), hh = (n0 + nl) >> 6;
        const int bb = m0 >> 11, tb = (m0 & (TT - 1)) + half * 64;
        const size_t gb = ((size_t)(bb * NHH + hh) * HSS + d) * TT + tb;
        #pragma unroll
        for (int t = 0; t < 8; ++t)
            *(uint4*)&Vt[gb + t * 8] = *(const uint4*)&XL[nl * 136 + half * 64 + t * 8];
    }
}

// ---------------------------------------------------------------------------
// attn: LDS-TRAFFIC-HALVED wave partition. Model: the LDS pipe is per-CU
// (128 ds_read_b128/CU/tile at ~12cyc = ~1540 cyc/tile = ~31us floor) and
// the old scheme had all 4 waves reading IDENTICAL X/V fragments. New
// partition: wave = (tile T in {A,B}) x (j-half H in {0,1}); each wave
// computes all 64 i of tile T over its 32-j half: 4 X-reads + 4 V-reads
// per tile (was 16), same MFMA count -> 2x arithmetic intensity vs LDS.
// All fragment layouts preserved from the R7-verified body (inner body is
// the per-nt body with nt->(H,nt2), w->iq; permlane pair-swap is the c=0
// half; V chunk gains +H*4). Partial (O,l) per j-half summed once at the
// end via padded LDS (OL stride 65 f32). Staging/double-buffer = R7.
// ---------------------------------------------------------------------------
__global__ __launch_bounds__(256) void attn_kernel(
    const u16* __restrict__ Xf, const u16* __restrict__ Kf,
    const u16* __restrict__ Vt, float* __restrict__ out)
{
    __shared__ __align__(16) u16 Xs[2][4096];  // x rows [j][d], chunk-swizzled
    __shared__ __align__(16) u16 Vs[2][4096];  // V^T [d][j], chunk-swizzled
    __shared__ float OL[2][64][65];            // per-tile O partial (pad 65)
    __shared__ float Ll[2][64];                // per-tile l partial

    const int L = blockIdx.x;
    const int xcd = L & 7, k = (L >> 3) & 15, grp = L >> 7;
    const int hb = xcd + 8 * grp;
    const int h = hb & (NHH - 1), b = hb >> 4;
    const int iA = k, iB = 31 - k;             // iB >= 16
    const int tid = threadIdx.x;
    const int w = tid >> 6, lane = tid & 63;
    const int T = w >> 1;                      // 0 = A-tile, 1 = B-tile
    const int H = w & 1;                       // j-half
    const int iT = T ? iB : iA;
    const int i0T = iT * 64;
    const int quad = lane >> 4, l15 = lane & 15;
    const int pq = ((quad & 1) << 1) | (quad >> 1);   // pi(quad)={0,2,1,3}
    const size_t rowbase = (size_t)b * TT;
    const int hd = h * HSS;
    const size_t vgbase = (size_t)(b * NHH + h) * HSS * TT;

    bf16x8 ones;
    { union { u32 u[4]; bf16x8 v; } o;
      #pragma unroll
      for (int i = 0; i < 4; ++i) o.u[i] = 0x3F803F80u;
      ones = o.v; }

    // Q (projected-K, log2e-scaled) fragments: 4 iq x 2 k-chunks for tile T
    f16x8 q[4][2];
    #pragma unroll
    for (int iq = 0; iq < 4; ++iq)
        #pragma unroll
        for (int c = 0; c < 2; ++c)
            q[iq][c] = *(const f16x8*)&Kf[(rowbase + i0T + iq * 16 + l15) * CC +
                                          hd + c * 32 + quad * 8];

    // gld16 staging descriptors (identical to R7): 2 chunks/lane/array
    int crow[2], ccg[2], cbase[2];
    #pragma unroll
    for (int t = 0; t < 2; ++t) {
        const int ci = t * 256 + tid;
        crow[t] = ci >> 3;
        ccg[t] = ((ci & 7) - crow[t]) & 7;
        cbase[t] = (t * 256 + w * 64) * 8;
    }
    const u16* gx[2]; const u16* gv[2];
    #pragma unroll
    for (int t = 0; t < 2; ++t) {
        gx[t] = Xf + (rowbase + crow[t]) * CC + hd + ccg[t] * 8;
        gv[t] = Vt + vgbase + (size_t)crow[t] * TT + ccg[t] * 8;
    }

    // prologue: stage tile 0 into buf 0
    #pragma unroll
    for (int t = 0; t < 2; ++t) {
        gld16(gx[t], Xs[0] + cbase[t]);
        gld16(gv[t], Vs[0] + cbase[t]);
    }

    f32x4 o[4][4] = {};    // [iq][dt]
    f32x4 la[4] = {};      // [iq]

    for (int jt = 0; jt <= iB; ++jt) {
        const int buf = jt & 1;
        __syncthreads();          // buf ready (vmcnt drained); prev reads done
        if (jt < iB) {
            const int j0n = (jt + 1) * 64;
            #pragma unroll
            for (int t = 0; t < 2; ++t) {
                gld16(gx[t] + (size_t)j0n * CC, Xs[buf ^ 1] + cbase[t]);
                gld16(gv[t] + j0n, Vs[buf ^ 1] + cbase[t]);
            }
        }
        if (jt > iT) continue;    // past this wave's diagonal: stage+sync only

        // ---- this wave's j-half fragments: 4 X + 4 V b128 reads ----
        f16x8 x[2][2];
        #pragma unroll
        for (int nt2 = 0; nt2 < 2; ++nt2) {
            const int krow = H * 32 + nt2 * 16 + l15;
            x[nt2][0] = *(const f16x8*)&Xs[buf][krow * 64 + ((quad + krow) & 7) * 8];
            x[nt2][1] = *(const f16x8*)&Xs[buf][krow * 64 + ((quad + 4 + krow) & 7) * 8];
        }
        bf16x8 v[4];
        #pragma unroll
        for (int dt = 0; dt < 4; ++dt) {
            const int vrow = dt * 16 + l15;
            v[dt] = *(const bf16x8*)&Vs[buf][vrow * 64 + ((H * 4 + pq + vrow) & 7) * 8];
        }

        const bool diag = (jt == iT);
        #pragma unroll
        for (int iq = 0; iq < 4; ++iq) {
            // S: lane (quad,l15) reg r = S[i = iq*16+l15][j = H*32+nt2*16+quad*4+r]
            f32x4 s[2];
            #pragma unroll
            for (int nt2 = 0; nt2 < 2; ++nt2) {
                f32x4 z = {S0INIT, S0INIT, S0INIT, S0INIT};
                z = MFMA_F16(x[nt2][0], q[iq][0], z);
                z = MFMA_F16(x[nt2][1], q[iq][1], z);
                s[nt2] = z;
            }
            if (diag) {
                #pragma unroll
                for (int nt2 = 0; nt2 < 2; ++nt2)
                    #pragma unroll
                    for (int r = 0; r < 4; ++r)
                        if (H * 32 + nt2 * 16 + quad * 4 + r > iq * 16 + l15)
                            s[nt2][r] = -1e30f;
            }
            // exp2 + pack + permlane pair-swap (c=0 half of the R7 path)
            u32 p_[2][2];
            #pragma unroll
            for (int nt2 = 0; nt2 < 2; ++nt2) {
                p_[nt2][0] = cvtpk_bf16(exp2f(s[nt2][0]), exp2f(s[nt2][1]));
                p_[nt2][1] = cvtpk_bf16(exp2f(s[nt2][2]), exp2f(s[nt2][3]));
            }
            #pragma unroll
            for (int p = 0; p < 2; ++p) {
                u32x2 sw = __builtin_amdgcn_permlane16_swap(
                    p_[0][p], p_[1][p], false, false);
                p_[0][p] = sw[0];
                p_[1][p] = sw[1];
            }
            union { u32 u[4]; bf16x8 vv; } ua;
            ua.u[0] = p_[0][0]; ua.u[1] = p_[0][1];
            ua.u[2] = p_[1][0]; ua.u[3] = p_[1][1];
            const bf16x8 a = ua.vv;

            la[iq] = MFMA_BF(a, ones, la[iq]);
            #pragma unroll
            for (int dt = 0; dt < 4; ++dt)
                o[iq][dt] = MFMA_BF(a, v[dt], o[iq][dt]);
        }
    }

    // ---- epilogue: sum j-halves via LDS, normalize, store ----
    __syncthreads();              // all compute done; Xs/Vs dead
    if (H == 1) {
        #pragma unroll
        for (int iq = 0; iq < 4; ++iq) {
            #pragma unroll
            for (int r = 0; r < 4; ++r) {
                const int il = iq * 16 + quad * 4 + r;
                if (l15 == 0) Ll[T][il] = la[iq][r];
                #pragma unroll
                for (int dt = 0; dt < 4; ++dt)
                    OL[T][il][dt * 16 + l15] = o[iq][dt][r];
            }
        }
    }
    __syncthreads();
    if (H == 0) {
        #pragma unroll
        for (int iq = 0; iq < 4; ++iq) {
            #pragma unroll
            for (int r = 0; r < 4; ++r) {
                const int il = iq * 16 + quad * 4 + r;
                const float inv = 1.f / (la[iq][r] + Ll[T][il]);
                const size_t rowoff = (rowbase + i0T + il) * CC + hd;
                #pragma unroll
                for (int dt = 0; dt < 4; ++dt)
                    out[rowoff + dt * 16 + l15] =
                        (o[iq][dt][r] + OL[T][il][dt * 16 + l15]) * inv;
            }
        }
    }
}

extern "C" void kernel_launch(void* const* d_in, const int* in_sizes, int n_in,
                              void* d_out, int out_size, void* d_ws, size_t ws_size,
                              hipStream_t stream) {
    (void)in_sizes; (void)n_in; (void)out_size; (void)ws_size;
    const float* x  = (const float*)d_in[0];
    const float* Wk = (const float*)d_in[1];
    const float* bk = (const float*)d_in[2];
    const float* Wv = (const float*)d_in[3];
    const float* bv = (const float*)d_in[4];
    float* out = (float*)d_out;

    const size_t M4 = (size_t)BT * CC;   // 4M elements
    const size_t M1 = (size_t)CC * CC;   // 1M elements
    u16* Xf  = (u16*)d_ws;               // fp16, 8 MB
    u16* Kf  = Xf + M4;                  // fp16 (log2e-scaled), 8 MB
    u16* Vt  = Kf + M4;                  // bf16, 8 MB
    u16* WkT = Vt + M4;                  // fp16, 2 MB
    u16* WvT = WkT + M1;                 // fp16, 2 MB  (28 MB total)

    convert_xw<<<dim3(2560), 256, 0, stream>>>(x, Wk, Wv, Xf, WkT, WvT);
    proj_kernel<<<dim3(512), 256, 0, stream>>>(Xf, WkT, WvT, bk, bv, Kf, Vt);
    attn_kernel<<<dim3(512), 256, 0, stream>>>(Xf, Kf, Vt, out);
}